// Round 6
// baseline (865.797 us; speedup 1.0000x reference)
//
#include <hip/hip_runtime.h>

typedef unsigned int u32;
typedef unsigned long long u64;

#define R_ROUNDS 64
#define HID 256
#define BATCH 16384
#define RPW 2   // batch rows per wave (2 -> 8192 waves, 2048 blocks, 8 blocks/CU)

// ---------------------------------------------------------------------------
// GF(2) reduction of the reference:
//   s' = (floor(s@M^T + n)) mod 2, s,n in {0,1}, M in {-1,0,1}
//      = parity(popcount(s & (M!=0) row)) XOR n        (-1 == 1 mod 2)
//
// pi-order packing: lane l owns bits {4l..4l+3}; packed u64 word k has
// bit l = vector bit (4l+k). All float traffic is dwordx4-coalesced.
//
// Round 6 = round-3 skeleton (best known: LDS-staged masks, depth-1 noise
// prefetch, __syncthreads per round) with DOUBLED block-level parallelism:
// RPW 4->2 gives 2048 blocks = 8 independent barrier domains per CU
// (32 waves/CU, the max), so one block's barrier drain overlaps other
// blocks' compute+loads. Register-economized (i-outer RUN, 8-VGPR mask
// liveness, 16-VGPR noise dbuf) to fit the 64-VGPR cap of
// __launch_bounds__(256, 8) without spill.
// ---------------------------------------------------------------------------

// Pack ternary matrices -> pi-ordered bitmasks. One wave per (r,j) row.
// P[row*8 + 2i+h] = half h of u64 W_i, where W_i bit l = (M[row][4l+i]!=0).
__global__ __launch_bounds__(256) void pack_matrices_kernel(
        const float* __restrict__ M, u32* __restrict__ P) {
    const int lane = threadIdx.x & 63;
    const int row  = (int)((blockIdx.x * blockDim.x + threadIdx.x) >> 6);
    const float4 v = *(const float4*)(M + (size_t)row * HID + 4 * lane);
    const u64 b0 = __ballot(v.x != 0.0f);
    const u64 b1 = __ballot(v.y != 0.0f);
    const u64 b2 = __ballot(v.z != 0.0f);
    const u64 b3 = __ballot(v.w != 0.0f);
    if (lane < 8) {
        const int i = lane >> 1;
        u64 bb = b0;
        if (i == 1) bb = b1;
        if (i == 2) bb = b2;
        if (i == 3) bb = b3;
        P[row * 8 + lane] = (lane & 1) ? (u32)(bb >> 32) : (u32)bb;
    }
}

__global__ __launch_bounds__(256, 8) void tenshash_kernel(
        const float* __restrict__ state,
        const u32*  __restrict__ pA,
        const float* __restrict__ noise,
        float* __restrict__ out) {
    const int lane = threadIdx.x & 63;
    const int warp = threadIdx.x >> 6;
    const int wave = (int)(blockIdx.x * 4 + warp);
    const int row0 = wave * RPW;

    __shared__ u32 smem[2][2048];   // 2 x 8KB mask double-buffer

    // ---- init state (pi-order): S[rw][k] bit l = state bit (4l+k) ----
    // Ballot results are wave-uniform -> live in SGPRs, not VGPRs.
    u64 S[RPW][4];
#pragma unroll
    for (int rw = 0; rw < RPW; ++rw) {
        const float4 v = *(const float4*)(state + (size_t)(row0 + rw) * HID + 4 * lane);
        S[rw][0] = __ballot(v.x != 0.0f);
        S[rw][1] = __ballot(v.y != 0.0f);
        S[rw][2] = __ballot(v.z != 0.0f);
        S[rw][3] = __ballot(v.w != 0.0f);
    }

    const float* no_l = noise + (size_t)row0 * (R_ROUNDS * HID) + 4 * lane;

    // Source-side swizzle: LDS 16B-slot u' = 64*t + lane holds global chunk
    // 64t + 8a + (b^a), a=lane>>3, b=lane&7 (inverse of the read swizzle).
    const int sa = lane >> 3, sb = lane & 7;
    const int src_chunk_lo = (sa << 3) + (sb ^ sa);

    // Stage round r's 8KB mask block into buffer b; each of the 4 waves
    // stages 2 of the 8 1KB chunks (2 x global_load_lds of 16B/lane).
    auto STAGE = [&](int r, int b) {
        const char* g = (const char*)(pA + (size_t)r * 2048);
#pragma unroll
        for (int t = 2 * warp; t < 2 * warp + 2; ++t) {
            __builtin_amdgcn_global_load_lds(
                (const __attribute__((address_space(1))) void*)
                    (g + t * 1024 + src_chunk_lo * 16),
                (__attribute__((address_space(3))) void*)&smem[b][t * 256],
                16, 0, 0);
        }
    };
    auto LOADN = [&](float4* n, int r) {
#pragma unroll
        for (int rw = 0; rw < RPW; ++rw)
            n[rw] = *(const float4*)(no_l + (size_t)rw * (R_ROUNDS * HID) + r * HID);
    };
    // RUN, i-outer: per output-bit-group i, read the 2 mask chunks (8 VGPRs
    // live), consume for both rows, then move on. Swizzled LDS read: chunk
    // (8*lane + t) lives at 16B-slot 8*lane + (t ^ (lane&7)) -> 2-way only.
    auto RUN = [&](const u32* base, const float4* n) {
        const uint4* p = (const uint4*)base;
        u64 ns[RPW][4];                       // wave-uniform -> SGPRs
#pragma unroll
        for (int i = 0; i < 4; ++i) {
            const uint4 a0 = p[(lane << 3) + ((2 * i)     ^ (lane & 7))];
            const uint4 a1 = p[(lane << 3) + ((2 * i + 1) ^ (lane & 7))];
            const u64 W0 = (u64)a0.x | ((u64)a0.y << 32);
            const u64 W1 = (u64)a0.z | ((u64)a0.w << 32);
            const u64 W2 = (u64)a1.x | ((u64)a1.y << 32);
            const u64 W3 = (u64)a1.z | ((u64)a1.w << 32);
#pragma unroll
            for (int rw = 0; rw < RPW; ++rw) {
                const float nfv = (i == 0) ? n[rw].x : (i == 1) ? n[rw].y
                                : (i == 2) ? n[rw].z : n[rw].w;
                const u32 c = (u32)__popcll(W0 & S[rw][0]) + (u32)__popcll(W1 & S[rw][1])
                            + (u32)__popcll(W2 & S[rw][2]) + (u32)__popcll(W3 & S[rw][3])
                            + (u32)nfv;               // exact: nfv in {0.0,1.0}
                ns[rw][i] = __ballot((c & 1u) != 0);
            }
        }
#pragma unroll
        for (int rw = 0; rw < RPW; ++rw)
#pragma unroll
            for (int k = 0; k < 4; ++k) S[rw][k] = ns[rw][k];
    };

    float4 nA[RPW], nB[RPW];

    // ---- prologue ----
    STAGE(0, 0);
    LOADN(nA, 0);
    __syncthreads();
#pragma unroll 1
    for (int r = 0; r < R_ROUNDS; r += 2) {
        STAGE(r + 1, 1);                  // r+1 <= 63 always
        LOADN(nB, r + 1);
        RUN(&smem[0][0], nA);             // round r
        __syncthreads();                  // buf1 + nB ready
        if (r + 2 < R_ROUNDS) {
            STAGE(r + 2, 0);
            LOADN(nA, r + 2);
        }
        RUN(&smem[1][0], nB);             // round r+1
        __syncthreads();                  // buf0 + nA ready
    }

    // ---- unpack final state, float4 stores ----
#pragma unroll
    for (int rw = 0; rw < RPW; ++rw) {
        float4 o;
        o.x = (float)((u32)(S[rw][0] >> lane) & 1u);
        o.y = (float)((u32)(S[rw][1] >> lane) & 1u);
        o.z = (float)((u32)(S[rw][2] >> lane) & 1u);
        o.w = (float)((u32)(S[rw][3] >> lane) & 1u);
        *(float4*)(out + (size_t)(row0 + rw) * HID + 4 * lane) = o;
    }
}

extern "C" void kernel_launch(void* const* d_in, const int* in_sizes, int n_in,
                              void* d_out, int out_size, void* d_ws, size_t ws_size,
                              hipStream_t stream) {
    const float* state = (const float*)d_in[0];
    const float* mats  = (const float*)d_in[1];
    const float* noise = (const float*)d_in[2];
    float* out         = (float*)d_out;
    u32* pA            = (u32*)d_ws;              // 512 KB packed masks

    pack_matrices_kernel<<<(R_ROUNDS * HID) / 4, 256, 0, stream>>>(mats, pA);

    const int blocks = (BATCH / RPW) / 4;         // 2048 blocks x 4 waves
    tenshash_kernel<<<blocks, 256, 0, stream>>>(state, pA, noise, out);
}

// Round 7
// 342.070 us; speedup vs baseline: 2.5311x; 2.5311x over previous
//
#include <hip/hip_runtime.h>

typedef unsigned int u32;
typedef unsigned long long u64;

#define R_ROUNDS 64
#define HID 256
#define BATCH 16384
#define RPW 2   // batch rows per wave -> 8192 waves, 2048 blocks, 32 waves/CU

// ---------------------------------------------------------------------------
// GF(2) reduction of the reference:
//   s' = (floor(s@M^T + n)) mod 2, s,n in {0,1}, M in {-1,0,1}
//      = parity(popcount(s & (M!=0) row)) XOR n        (-1 == 1 mod 2)
//
// pi-order: lane l owns output bits {4l..4l+3}; packed u64 word k of the
// state has bit l = vector bit (4l+k). Noise/state/out are float4 per lane.
//
// Round 7: BARRIER-FREE. No LDS, no __syncthreads, no launch_bounds (the
// forced VGPR cap was R2/R6's spill poison). Each wave holds its round's
// mask rows in 8 uint4 registers, loaded as 8 perfectly-coalesced 1KB
// dwordx4 bursts from a TRANSPOSED packed layout (chunk t, lane l at
// t*1024 + l*16 within each round's 8KB block; L2-resident). Waves stall
// privately on their own vmcnt -> with 32 waves/CU the HBM queue never
// collectively drains.
// ---------------------------------------------------------------------------

// Pack ternary matrices -> pi-ordered, round-transposed bitmasks in d_ws.
// Round r's 8KB block: u32 P[r*2048 + t*256 + l*4 + q] = u32 (4h+q) of the
// mask row (4l+i), where t = 2i+h. Row u32 layout: [W0lo,W0hi,...,W3lo,W3hi],
// W_k bit l = (M[row][4l+k] != 0).
__global__ __launch_bounds__(256) void pack_matrices_kernel(
        const float* __restrict__ M, u32* __restrict__ P) {
    const int lane = threadIdx.x & 63;
    const int gw   = (int)((blockIdx.x * blockDim.x + threadIdx.x) >> 6); // row 0..16383
    const int r    = gw >> 8;      // round
    const int jj   = gw & 255;     // row within round
    const float4 v = *(const float4*)(M + (size_t)gw * HID + 4 * lane);
    const u64 b0 = __ballot(v.x != 0.0f);   // W0: bit l = (M[jj][4l+0] != 0)
    const u64 b1 = __ballot(v.y != 0.0f);
    const u64 b2 = __ballot(v.z != 0.0f);
    const u64 b3 = __ballot(v.w != 0.0f);
    if (lane < 8) {
        const int w = lane;                 // u32-in-row index 0..7
        u64 bb = b0;                        // W_{w>>1}
        if ((w >> 1) == 1) bb = b1;
        if ((w >> 1) == 2) bb = b2;
        if ((w >> 1) == 3) bb = b3;
        const u32 val = (w & 1) ? (u32)(bb >> 32) : (u32)bb;
        const int t = 2 * (jj & 3) + (w >> 2);          // chunk index 0..7
        P[r * 2048 + t * 256 + (jj >> 2) * 4 + (w & 3)] = val;
    }
}

__global__ void tenshash_kernel(
        const float* __restrict__ state,
        const u32*  __restrict__ pA,
        const float* __restrict__ noise,
        float* __restrict__ out) {
    const int lane = threadIdx.x & 63;
    const int wave = (int)((blockIdx.x * blockDim.x + threadIdx.x) >> 6);
    const int row0 = wave * RPW;

    // ---- init state (pi-order): S[rw][k] bit l = state bit (4l+k) ----
    // Ballot results are wave-uniform -> SGPRs.
    u64 S[RPW][4];
#pragma unroll
    for (int rw = 0; rw < RPW; ++rw) {
        const float4 v = *(const float4*)(state + (size_t)(row0 + rw) * HID + 4 * lane);
        S[rw][0] = __ballot(v.x != 0.0f);
        S[rw][1] = __ballot(v.y != 0.0f);
        S[rw][2] = __ballot(v.z != 0.0f);
        S[rw][3] = __ballot(v.w != 0.0f);
    }

    const float* no_l = noise + (size_t)row0 * (R_ROUNDS * HID) + 4 * lane;
    const uint4* pm   = (const uint4*)pA;   // m[t] = pm[r*512 + t*64 + lane]

#pragma unroll 1
    for (int r = 0; r < R_ROUNDS; ++r) {
        // noise first (HBM, ~900cyc) so its latency overlaps the L2 mask
        // loads and the mask-side compute below.
        float4 n[RPW];
#pragma unroll
        for (int rw = 0; rw < RPW; ++rw)
            n[rw] = *(const float4*)(no_l + (size_t)rw * (R_ROUNDS * HID) + r * HID);

        // 8 coalesced 1KB bursts: lane l's chunk t = 16B of mask rows 4l..4l+3.
        uint4 m[8];
        const uint4* pr = pm + r * 512 + lane;
#pragma unroll
        for (int t = 0; t < 8; ++t) m[t] = pr[t * 64];

        u64 ns[RPW][4];
#pragma unroll
        for (int i = 0; i < 4; ++i) {        // output bit j = 4l+i, row 4l+i
            const uint4 a0 = m[2 * i];       // [W0lo,W0hi,W1lo,W1hi] of row 4l+i
            const uint4 a1 = m[2 * i + 1];   // [W2lo,W2hi,W3lo,W3hi]
            const u64 W0 = (u64)a0.x | ((u64)a0.y << 32);
            const u64 W1 = (u64)a0.z | ((u64)a0.w << 32);
            const u64 W2 = (u64)a1.x | ((u64)a1.y << 32);
            const u64 W3 = (u64)a1.z | ((u64)a1.w << 32);
#pragma unroll
            for (int rw = 0; rw < RPW; ++rw) {
                const float nfv = (i == 0) ? n[rw].x : (i == 1) ? n[rw].y
                                : (i == 2) ? n[rw].z : n[rw].w;
                const u32 c = (u32)__popcll(W0 & S[rw][0]) + (u32)__popcll(W1 & S[rw][1])
                            + (u32)__popcll(W2 & S[rw][2]) + (u32)__popcll(W3 & S[rw][3])
                            + (u32)nfv;               // exact: nfv in {0.0,1.0}
                ns[rw][i] = __ballot((c & 1u) != 0);
            }
        }
#pragma unroll
        for (int rw = 0; rw < RPW; ++rw)
#pragma unroll
            for (int k = 0; k < 4; ++k) S[rw][k] = ns[rw][k];
    }

    // ---- unpack final state, float4 stores ----
#pragma unroll
    for (int rw = 0; rw < RPW; ++rw) {
        float4 o;
        o.x = (float)((u32)(S[rw][0] >> lane) & 1u);
        o.y = (float)((u32)(S[rw][1] >> lane) & 1u);
        o.z = (float)((u32)(S[rw][2] >> lane) & 1u);
        o.w = (float)((u32)(S[rw][3] >> lane) & 1u);
        *(float4*)(out + (size_t)(row0 + rw) * HID + 4 * lane) = o;
    }
}

extern "C" void kernel_launch(void* const* d_in, const int* in_sizes, int n_in,
                              void* d_out, int out_size, void* d_ws, size_t ws_size,
                              hipStream_t stream) {
    const float* state = (const float*)d_in[0];
    const float* mats  = (const float*)d_in[1];
    const float* noise = (const float*)d_in[2];
    float* out         = (float*)d_out;
    u32* pA            = (u32*)d_ws;              // 512 KB packed masks

    // one wave per matrix row -> 16384 waves, 4096 blocks
    pack_matrices_kernel<<<(R_ROUNDS * HID) / 4, 256, 0, stream>>>(mats, pA);

    // barrier-free main: 8192 waves, 2048 blocks of 256 threads
    const int blocks = (BATCH / RPW) / 4;
    tenshash_kernel<<<blocks, 256, 0, stream>>>(state, pA, noise, out);
}

// Round 8
// 234.424 us; speedup vs baseline: 3.6933x; 1.4592x over previous
//
#include <hip/hip_runtime.h>

typedef unsigned int u32;
typedef unsigned long long u64;

#define R_ROUNDS 64
#define HID 256
#define BATCH 16384
#define RPW 4   // batch rows per wave

// ---------------------------------------------------------------------------
// GF(2) reduction of the reference:
//   s' = (floor(s@M^T + n)) mod 2, s,n in {0,1}, M in {-1,0,1}
//      = parity(popcount(s & (M!=0) row)) XOR n        (-1 == 1 mod 2)
//
// pi-order: lane l owns output bits {4l..4l+3}; packed u64 word k of the
// state has bit l = vector bit (4l+k). Noise/state/out are float4 per lane.
//
// Round 8 = round-3 skeleton (best known: LDS-staged masks, depth-1
// prefetch, __syncthreads per round, 4 blocks/CU) with the measured waste
// removed:
//  - round-transposed packed-mask layout (HW-validated in round 7):
//    staging is linear-global -> linear-LDS (no swizzle on either side),
//    and RUN's ds_read_b128 sweep is CONTIGUOUS per chunk -> each
//    quarter-wave covers all 32 banks exactly twice = conflict-free
//    (round-6 counters showed the old XOR-swizzled pattern cost ~4 extra
//    cyc per ds_read_b128, SQ_LDS_BANK_CONFLICT = 1.68e7).
//  - noise (HBM, long latency) issued before mask staging (L2, short).
//  - staging split 2 chunks/wave (symmetric vmcnt at the barrier).
// ---------------------------------------------------------------------------

// Pack ternary matrices -> pi-ordered, round-transposed bitmasks in d_ws.
// Round r's 8KB block: u32 P[r*2048 + t*256 + l*4 + q] = u32 (4h+q) of
// mask row (4l+i), where t = 2i+h; row u32 layout [W0lo,W0hi,...,W3lo,W3hi],
// W_k bit l = (M[row][4l+k] != 0).   (Byte-identical to round 7's pack.)
__global__ __launch_bounds__(256) void pack_matrices_kernel(
        const float* __restrict__ M, u32* __restrict__ P) {
    const int lane = threadIdx.x & 63;
    const int gw   = (int)((blockIdx.x * blockDim.x + threadIdx.x) >> 6); // row 0..16383
    const int r    = gw >> 8;      // round
    const int jj   = gw & 255;     // row within round
    const float4 v = *(const float4*)(M + (size_t)gw * HID + 4 * lane);
    const u64 b0 = __ballot(v.x != 0.0f);
    const u64 b1 = __ballot(v.y != 0.0f);
    const u64 b2 = __ballot(v.z != 0.0f);
    const u64 b3 = __ballot(v.w != 0.0f);
    if (lane < 8) {
        const int w = lane;                 // u32-in-row index 0..7
        u64 bb = b0;
        if ((w >> 1) == 1) bb = b1;
        if ((w >> 1) == 2) bb = b2;
        if ((w >> 1) == 3) bb = b3;
        const u32 val = (w & 1) ? (u32)(bb >> 32) : (u32)bb;
        const int t = 2 * (jj & 3) + (w >> 2);          // chunk index 0..7
        P[r * 2048 + t * 256 + (jj >> 2) * 4 + (w & 3)] = val;
    }
}

__global__ __launch_bounds__(256, 4) void tenshash_kernel(
        const float* __restrict__ state,
        const u32*  __restrict__ pA,
        const float* __restrict__ noise,
        float* __restrict__ out) {
    const int lane = threadIdx.x & 63;
    const int warp = threadIdx.x >> 6;
    const int wave = (int)(blockIdx.x * 4 + warp);
    const int row0 = wave * RPW;

    __shared__ u32 smem[2][2048];   // 2 x 8KB mask double-buffer

    // ---- init state (pi-order): S[rw][k] bit l = state bit (4l+k) ----
    u64 S0[RPW], S1[RPW], S2[RPW], S3[RPW];
#pragma unroll
    for (int rw = 0; rw < RPW; ++rw) {
        const float4 v = *(const float4*)(state + (size_t)(row0 + rw) * HID + 4 * lane);
        S0[rw] = __ballot(v.x != 0.0f);
        S1[rw] = __ballot(v.y != 0.0f);
        S2[rw] = __ballot(v.z != 0.0f);
        S3[rw] = __ballot(v.w != 0.0f);
    }

    const float* no_l = noise + (size_t)row0 * (R_ROUNDS * HID) + 4 * lane;

    // Stage round r's 8KB (already round-transposed, so LINEAR both sides):
    // each of the 4 waves stages 2 of the 8 1KB chunks.
    auto STAGE = [&](int r, int b) {
        const char* g = (const char*)(pA + (size_t)r * 2048);
#pragma unroll
        for (int t = 2 * warp; t < 2 * warp + 2; ++t) {
            __builtin_amdgcn_global_load_lds(
                (const __attribute__((address_space(1))) void*)
                    (g + t * 1024 + lane * 16),
                (__attribute__((address_space(3))) void*)&smem[b][t * 256],
                16, 0, 0);
        }
    };
    auto LOADN = [&](float4* n, int r) {
#pragma unroll
        for (int rw = 0; rw < RPW; ++rw)
            n[rw] = *(const float4*)(no_l + (size_t)rw * (R_ROUNDS * HID) + r * HID);
    };
    // Contiguous LDS read: chunk t's lane-l slot at uint4 index t*64 + lane
    // (byte t*1024 + 16l) -> each quarter-wave spans all 32 banks twice:
    // conflict-free.  a[2i],a[2i+1] = the 8 u32s of mask row (4l+i).
    auto RUN = [&](const u32* base, const float4* n) {
        const uint4* p = (const uint4*)base;
        uint4 a[8];
#pragma unroll
        for (int t = 0; t < 8; ++t)
            a[t] = p[(t << 6) + lane];
#pragma unroll
        for (int rw = 0; rw < RPW; ++rw) {
            u64 ns0, ns1, ns2, ns3;
#pragma unroll
            for (int i = 0; i < 4; ++i) {
                const u64 W0 = (u64)a[2 * i].x     | ((u64)a[2 * i].y     << 32);
                const u64 W1 = (u64)a[2 * i].z     | ((u64)a[2 * i].w     << 32);
                const u64 W2 = (u64)a[2 * i + 1].x | ((u64)a[2 * i + 1].y << 32);
                const u64 W3 = (u64)a[2 * i + 1].z | ((u64)a[2 * i + 1].w << 32);
                const float nfv = (i == 0) ? n[rw].x : (i == 1) ? n[rw].y
                                : (i == 2) ? n[rw].z : n[rw].w;
                const u32 c = (u32)__popcll(W0 & S0[rw]) + (u32)__popcll(W1 & S1[rw])
                            + (u32)__popcll(W2 & S2[rw]) + (u32)__popcll(W3 & S3[rw])
                            + (u32)nfv;                    // exact: nfv in {0.0,1.0}
                const u64 nb = __ballot((c & 1u) != 0);
                if (i == 0) ns0 = nb; else if (i == 1) ns1 = nb;
                else if (i == 2) ns2 = nb; else ns3 = nb;
            }
            S0[rw] = ns0; S1[rw] = ns1; S2[rw] = ns2; S3[rw] = ns3;
        }
    };

    float4 nA[RPW], nB[RPW];

    // ---- prologue ----
    LOADN(nA, 0);
    STAGE(0, 0);
    __syncthreads();
#pragma unroll 1
    for (int r = 0; r < R_ROUNDS; r += 2) {
        LOADN(nB, r + 1);                 // HBM first (longest latency)
        STAGE(r + 1, 1);                  // then L2 mask stage
        RUN(&smem[0][0], nA);             // round r
        __syncthreads();                  // buf1 + nB ready
        if (r + 2 < R_ROUNDS) {
            LOADN(nA, r + 2);
            STAGE(r + 2, 0);
        }
        RUN(&smem[1][0], nB);             // round r+1
        __syncthreads();                  // buf0 + nA ready
    }

    // ---- unpack final state, float4 stores ----
#pragma unroll
    for (int rw = 0; rw < RPW; ++rw) {
        float4 o;
        o.x = (float)((u32)(S0[rw] >> lane) & 1u);
        o.y = (float)((u32)(S1[rw] >> lane) & 1u);
        o.z = (float)((u32)(S2[rw] >> lane) & 1u);
        o.w = (float)((u32)(S3[rw] >> lane) & 1u);
        *(float4*)(out + (size_t)(row0 + rw) * HID + 4 * lane) = o;
    }
}

extern "C" void kernel_launch(void* const* d_in, const int* in_sizes, int n_in,
                              void* d_out, int out_size, void* d_ws, size_t ws_size,
                              hipStream_t stream) {
    const float* state = (const float*)d_in[0];
    const float* mats  = (const float*)d_in[1];
    const float* noise = (const float*)d_in[2];
    float* out         = (float*)d_out;
    u32* pA            = (u32*)d_ws;              // 512 KB packed masks

    pack_matrices_kernel<<<(R_ROUNDS * HID) / 4, 256, 0, stream>>>(mats, pA);

    const int blocks = (BATCH / RPW) / 4;         // 1024 blocks x 4 waves
    tenshash_kernel<<<blocks, 256, 0, stream>>>(state, pA, noise, out);
}

// Round 9
// 228.000 us; speedup vs baseline: 3.7974x; 1.0282x over previous
//
#include <hip/hip_runtime.h>

typedef unsigned int u32;
typedef unsigned long long u64;

#define R_ROUNDS 64
#define HID 256
#define BATCH 16384
#define RPW 4   // batch rows per wave

// ---------------------------------------------------------------------------
// GF(2) reduction of the reference:
//   s' = (floor(s@M^T + n)) mod 2, s,n in {0,1}, M in {-1,0,1}
//      = parity(popcount(s & (M!=0) row)) XOR n        (-1 == 1 mod 2)
//
// pi-order: lane l owns output bits {4l..4l+3}; packed u64 word k of the
// state has bit l = vector bit (4l+k). Noise/state/out are float4 per lane.
//
// Round 9 = round-8 skeleton with COUNTED-DRAIN sync (the m201/HK pattern,
// minimal fencing -- unlike round 4's sched_barrier spam):
//   per phase: {STAGE(r+2) 2 loads; LOADN(r+2) 4 loads; RUN(r);
//               s_waitcnt vmcnt(6); s_barrier; sched_barrier(0)}
// vmcnt(6) retires exactly the PREVIOUS phase's 6 VMEM ops, so every load
// gets ~2 phases (~1600cyc) in flight and the HBM queue never drains to 0
// (__syncthreads' implicit vmcnt(0) did, once per round -- and made any
// prefetch distance >1 impossible, which is why R5 was neutral).
// Quad-buffered LDS: stage->use distance 2, reuse distance 4. Barrier skew
// is 0 at each phase boundary, so cross-wave buffer reuse is race-free.
// ---------------------------------------------------------------------------

// Pack ternary matrices -> pi-ordered, round-transposed bitmasks in d_ws.
// Round r's 8KB block: u32 P[r*2048 + t*256 + l*4 + q] = u32 (4h+q) of
// mask row (4l+i), where t = 2i+h; row u32 layout [W0lo,W0hi,...,W3lo,W3hi],
// W_k bit l = (M[row][4l+k] != 0).   (Byte-identical to rounds 7/8.)
__global__ __launch_bounds__(256) void pack_matrices_kernel(
        const float* __restrict__ M, u32* __restrict__ P) {
    const int lane = threadIdx.x & 63;
    const int gw   = (int)((blockIdx.x * blockDim.x + threadIdx.x) >> 6); // row 0..16383
    const int r    = gw >> 8;      // round
    const int jj   = gw & 255;     // row within round
    const float4 v = *(const float4*)(M + (size_t)gw * HID + 4 * lane);
    const u64 b0 = __ballot(v.x != 0.0f);
    const u64 b1 = __ballot(v.y != 0.0f);
    const u64 b2 = __ballot(v.z != 0.0f);
    const u64 b3 = __ballot(v.w != 0.0f);
    if (lane < 8) {
        const int w = lane;                 // u32-in-row index 0..7
        u64 bb = b0;
        if ((w >> 1) == 1) bb = b1;
        if ((w >> 1) == 2) bb = b2;
        if ((w >> 1) == 3) bb = b3;
        const u32 val = (w & 1) ? (u32)(bb >> 32) : (u32)bb;
        const int t = 2 * (jj & 3) + (w >> 2);          // chunk index 0..7
        P[r * 2048 + t * 256 + (jj >> 2) * 4 + (w & 3)] = val;
    }
}

__global__ __launch_bounds__(256, 4) void tenshash_kernel(
        const float* __restrict__ state,
        const u32*  __restrict__ pA,
        const float* __restrict__ noise,
        float* __restrict__ out) {
    const int lane = threadIdx.x & 63;
    const int warp = threadIdx.x >> 6;
    const int wave = (int)(blockIdx.x * 4 + warp);
    const int row0 = wave * RPW;

    __shared__ u32 smem[4][2048];   // 4 x 8KB mask buffers, reuse distance 4

    // ---- init state (pi-order): S_k[rw] bit l = state bit (4l+k) ----
    u64 S0[RPW], S1[RPW], S2[RPW], S3[RPW];
#pragma unroll
    for (int rw = 0; rw < RPW; ++rw) {
        const float4 v = *(const float4*)(state + (size_t)(row0 + rw) * HID + 4 * lane);
        S0[rw] = __ballot(v.x != 0.0f);
        S1[rw] = __ballot(v.y != 0.0f);
        S2[rw] = __ballot(v.z != 0.0f);
        S3[rw] = __ballot(v.w != 0.0f);
    }

    const float* no_l = noise + (size_t)row0 * (R_ROUNDS * HID) + 4 * lane;

    // Stage round r's 8KB (transposed layout: LINEAR both sides):
    // each of the 4 waves stages 2 of the 8 1KB chunks = 2 VMEM ops.
    auto STAGE = [&](int r, int b) {
        const char* g = (const char*)(pA + (size_t)r * 2048);
#pragma unroll
        for (int t = 2 * warp; t < 2 * warp + 2; ++t) {
            __builtin_amdgcn_global_load_lds(
                (const __attribute__((address_space(1))) void*)
                    (g + t * 1024 + lane * 16),
                (__attribute__((address_space(3))) void*)&smem[b][t * 256],
                16, 0, 0);
        }
    };
    auto LOADN = [&](float4* n, int r) {      // 4 VMEM ops
#pragma unroll
        for (int rw = 0; rw < RPW; ++rw)
            n[rw] = *(const float4*)(no_l + (size_t)rw * (R_ROUNDS * HID) + r * HID);
    };
    // i-outer RUN (8 live mask VGPRs; bit-exact-validated in round 6):
    // chunk t at uint4 slot t*64+lane; a0/a1 = the 8 u32s of mask row 4l+i.
    auto RUN = [&](const u32* base, const float4* n) {
        const uint4* p = (const uint4*)base;
        u64 ns0[RPW], ns1[RPW], ns2[RPW], ns3[RPW];
#pragma unroll
        for (int i = 0; i < 4; ++i) {
            const uint4 a0 = p[((2 * i) << 6) + lane];
            const uint4 a1 = p[((2 * i + 1) << 6) + lane];
            const u64 W0 = (u64)a0.x | ((u64)a0.y << 32);
            const u64 W1 = (u64)a0.z | ((u64)a0.w << 32);
            const u64 W2 = (u64)a1.x | ((u64)a1.y << 32);
            const u64 W3 = (u64)a1.z | ((u64)a1.w << 32);
#pragma unroll
            for (int rw = 0; rw < RPW; ++rw) {
                const float nfv = (i == 0) ? n[rw].x : (i == 1) ? n[rw].y
                                : (i == 2) ? n[rw].z : n[rw].w;
                const u32 c = (u32)__popcll(W0 & S0[rw]) + (u32)__popcll(W1 & S1[rw])
                            + (u32)__popcll(W2 & S2[rw]) + (u32)__popcll(W3 & S3[rw])
                            + (u32)nfv;                    // exact: nfv in {0.0,1.0}
                const u64 nb = __ballot((c & 1u) != 0);
                if (i == 0) ns0[rw] = nb; else if (i == 1) ns1[rw] = nb;
                else if (i == 2) ns2[rw] = nb; else ns3[rw] = nb;
            }
        }
#pragma unroll
        for (int rw = 0; rw < RPW; ++rw) {
            S0[rw] = ns0[rw]; S1[rw] = ns1[rw];
            S2[rw] = ns2[rw]; S3[rw] = ns3[rw];
        }
    };

    float4 n0[RPW], n1[RPW], n2[RPW], n3[RPW];

    // ---- prologue: two phases' worth of loads; retire the first 6 ----
    STAGE(0, 0); LOADN(n0, 0);        // L_{-2}: 6 VMEM
    STAGE(1, 1); LOADN(n1, 1);        // L_{-1}: 6 VMEM
    asm volatile("s_waitcnt vmcnt(6)" ::: "memory");   // L_{-2} retired
    __builtin_amdgcn_s_barrier();
    __builtin_amdgcn_sched_barrier(0);

    // Phase k (round r+k): stage r+k+2 -> buf (k+2)&3, noise r+k+2 -> NLOAD;
    // compute round r+k from buf k / NUSE; retire previous phase's 6 loads.
#define PHASE(k, NUSE, NLOAD)                                            \
    {                                                                    \
        int rs = r + k + 2; if (rs > R_ROUNDS - 1) rs = R_ROUNDS - 1;    \
        STAGE(rs, (k + 2) & 3);                                          \
        LOADN(NLOAD, rs);                                                \
        RUN(&smem[k][0], NUSE);                                          \
        asm volatile("s_waitcnt vmcnt(6)" ::: "memory");                 \
        __builtin_amdgcn_s_barrier();                                    \
        __builtin_amdgcn_sched_barrier(0);                               \
    }

#pragma unroll 1
    for (int r = 0; r < R_ROUNDS; r += 4) {
        PHASE(0, n0, n2)
        PHASE(1, n1, n3)
        PHASE(2, n2, n0)
        PHASE(3, n3, n1)
    }
#undef PHASE

    // ---- unpack final state, float4 stores ----
#pragma unroll
    for (int rw = 0; rw < RPW; ++rw) {
        float4 o;
        o.x = (float)((u32)(S0[rw] >> lane) & 1u);
        o.y = (float)((u32)(S1[rw] >> lane) & 1u);
        o.z = (float)((u32)(S2[rw] >> lane) & 1u);
        o.w = (float)((u32)(S3[rw] >> lane) & 1u);
        *(float4*)(out + (size_t)(row0 + rw) * HID + 4 * lane) = o;
    }
}

extern "C" void kernel_launch(void* const* d_in, const int* in_sizes, int n_in,
                              void* d_out, int out_size, void* d_ws, size_t ws_size,
                              hipStream_t stream) {
    const float* state = (const float*)d_in[0];
    const float* mats  = (const float*)d_in[1];
    const float* noise = (const float*)d_in[2];
    float* out         = (float*)d_out;
    u32* pA            = (u32*)d_ws;              // 512 KB packed masks

    pack_matrices_kernel<<<(R_ROUNDS * HID) / 4, 256, 0, stream>>>(mats, pA);

    const int blocks = (BATCH / RPW) / 4;         // 1024 blocks x 4 waves
    tenshash_kernel<<<blocks, 256, 0, stream>>>(state, pA, noise, out);
}